// Round 9
// baseline (564.287 us; speedup 1.0000x reference)
//
#include <hip/hip_runtime.h>

#define H96 96

typedef __attribute__((ext_vector_type(8))) short bf16x8_t;
typedef __attribute__((ext_vector_type(4))) float f32x4_t;

// ---------------- degrees (int) ----------------
__global__ void deg_kernel(const int* __restrict__ src, const int* __restrict__ dst,
                           int* __restrict__ dout, int* __restrict__ din, int E) {
    int e = blockIdx.x * blockDim.x + threadIdx.x;
    if (e < E) {
        atomicAdd(dout + src[e], 1);
        atomicAdd(din + dst[e], 1);
    }
}

__global__ void norm_kernel(const int* __restrict__ dO, const int* __restrict__ dI,
                            float* __restrict__ no, float* __restrict__ ni, int N) {
    int i = blockIdx.x * blockDim.x + threadIdx.x;
    if (i < N) {
        no[i] = rsqrtf(fmaxf((float)dO[i], 1.0f));
        ni[i] = rsqrtf(fmaxf((float)dI[i], 1.0f));
    }
}

// ---------------- generic exclusive scan (3 kernels, n <= 256*256) ----------------
__global__ void scanA_kernel(const int* __restrict__ in, int* __restrict__ pre,
                             int* __restrict__ bsums, int n) {
    __shared__ int s[256];
    int i = blockIdx.x * 256 + threadIdx.x;
    int v = (i < n) ? in[i] : 0;
    s[threadIdx.x] = v;
    __syncthreads();
    for (int off = 1; off < 256; off <<= 1) {
        int t = (threadIdx.x >= off) ? s[threadIdx.x - off] : 0;
        __syncthreads();
        s[threadIdx.x] += t;
        __syncthreads();
    }
    if (i < n) pre[i] = s[threadIdx.x] - v;
    if (threadIdx.x == 255) bsums[blockIdx.x] = s[255];
}

__global__ void scanB_kernel(int* __restrict__ bsums, int nb) {
    __shared__ int s[256];
    int v = (threadIdx.x < nb) ? bsums[threadIdx.x] : 0;
    s[threadIdx.x] = v;
    __syncthreads();
    for (int off = 1; off < 256; off <<= 1) {
        int t = (threadIdx.x >= off) ? s[threadIdx.x - off] : 0;
        __syncthreads();
        s[threadIdx.x] += t;
        __syncthreads();
    }
    if (threadIdx.x < nb) bsums[threadIdx.x] = s[threadIdx.x] - v;
}

__global__ void scanC_kernel(const int* __restrict__ pre, const int* __restrict__ bsums,
                             int* __restrict__ out, int n) {
    int i = blockIdx.x * 256 + threadIdx.x;
    if (i < n) out[i] = pre[i] + bsums[blockIdx.x];
}

__global__ void rowfin_kernel(const int* __restrict__ pre, const int* __restrict__ bsums,
                              int* __restrict__ row_start, int* __restrict__ cursor,
                              int N, int E) {
    int i = blockIdx.x * 256 + threadIdx.x;
    if (i < N) {
        int v = pre[i] + bsums[blockIdx.x];
        row_start[i] = v;
        cursor[i] = v;
    }
    if (i == 0) row_start[N] = E;
}

__global__ void scatter_kernel(const int* __restrict__ src, const int* __restrict__ dst,
                               int* __restrict__ cursor, int* __restrict__ csr_src, int E) {
    int e = blockIdx.x * 256 + threadIdx.x;
    if (e < E) {
        int d = dst[e];
        int p = atomicAdd(cursor + d, 1);
        csr_src[p] = src[e];
    }
}

// ---------------- low-contention counting sort by deg_in ----------------
__global__ void histblk_kernel(const int* __restrict__ deg, int* __restrict__ hb,
                               int N, int nb) {
    __shared__ int h[256];
    h[threadIdx.x] = 0;
    __syncthreads();
    int i = blockIdx.x * 256 + threadIdx.x;
    if (i < N) atomicAdd(&h[min(deg[i], 255)], 1);
    __syncthreads();
    hb[threadIdx.x * nb + blockIdx.x] = h[threadIdx.x];
}

__global__ void place_kernel(const int* __restrict__ deg, const int* __restrict__ hbs,
                             int* __restrict__ order, int N, int nb) {
    __shared__ int cur[256];
    cur[threadIdx.x] = hbs[threadIdx.x * nb + blockIdx.x];
    __syncthreads();
    int i = blockIdx.x * 256 + threadIdx.x;
    if (i < N) {
        int b = min(deg[i], 255);
        int p = atomicAdd(&cur[b], 1);
        order[p] = i;
    }
}

// wsum[c] = row sums of Wm, bsum = sum(bm)
__global__ void wsum_kernel(const float* __restrict__ Wm, const float* __restrict__ bm,
                            float* __restrict__ wsum, float* __restrict__ bsum) {
    int c = threadIdx.x;
    if (c < H96) {
        float s = 0.f;
        for (int j = 0; j < H96; j++) s += Wm[c * H96 + j];
        wsum[c] = s;
    }
    if (c == 0) {
        float s = 0.f;
        for (int j = 0; j < H96; j++) s += bm[j];
        bsum[0] = s;
    }
}

// ---------------- bf16 hi/lo split helper ----------------
__device__ __forceinline__ void f2bf2(float v, unsigned short& h, unsigned short& l) {
    unsigned int b = __float_as_uint(v);
    unsigned short hh = (unsigned short)((b + 0x7FFFu + ((b >> 16) & 1u)) >> 16);
    float fh = __uint_as_float(((unsigned int)hh) << 16);
    float r = v - fh;
    unsigned int rb = __float_as_uint(r);
    unsigned short ll = (unsigned short)((rb + 0x7FFFu + ((rb >> 16) & 1u)) >> 16);
    h = hh; l = ll;
}

// W[K][96] fp32 -> Bt_hi/Bt_lo [96][KP] bf16 (transposed, zero-padded to KP)
__global__ void convB_kernel(const float* __restrict__ W, unsigned short* __restrict__ Bh,
                             unsigned short* __restrict__ Bl, int K, int KP) {
    int idx = blockIdx.x * 256 + threadIdx.x;
    if (idx < 96 * KP) {
        int n = idx / KP, k = idx - n * KP;
        float v = (k < K) ? W[(size_t)k * 96 + n] : 0.f;
        unsigned short h, l;
        f2bf2(v, h, l);
        Bh[idx] = h;
        Bl[idx] = l;
    }
}

// ---------------- bf16x3 MFMA GEMM: C = A @ B, optional view-interleaved C rows ----------------
// If ilv > 0: input row r<ilv (view1 node r) -> C row 2r; row r>=ilv -> C row 2(r-ilv)+1.
#define GBM 128
#define GBK 32
#define ASTR2 40
__global__ __launch_bounds__(256) void gemm_mfma(const float* __restrict__ A,
                                                 const unsigned short* __restrict__ Bth,
                                                 const unsigned short* __restrict__ Btl,
                                                 float* __restrict__ C, int M, int K, int KP,
                                                 int ilv) {
    __shared__ unsigned short As_hi[GBM * ASTR2];
    __shared__ unsigned short As_lo[GBM * ASTR2];
    __shared__ unsigned short Bs_hi[96 * ASTR2];
    __shared__ unsigned short Bs_lo[96 * ASTR2];
    int tid = threadIdx.x;
    int row0 = blockIdx.x * GBM;
    int wid = tid >> 6, lane = tid & 63;
    int q = lane >> 4, mn = lane & 15;
    f32x4_t acc[2][6] = {};
    int nk = (K + GBK - 1) / GBK;

    for (int t = 0; t < nk; t++) {
        int k0 = t * GBK;
#pragma unroll
        for (int i = 0; i < 4; i++) {
            int idx = tid + i * 256;
            int r = idx >> 3, kq = idx & 7;
            int gr = row0 + r, gk = k0 + kq * 4;
            float4 v = make_float4(0.f, 0.f, 0.f, 0.f);
            if (gr < M) {
                if (gk + 4 <= K) {
                    v = *(const float4*)(A + (size_t)gr * K + gk);
                } else {
                    float tv[4] = {0.f, 0.f, 0.f, 0.f};
                    for (int c = 0; c < 4; c++)
                        if (gk + c < K) tv[c] = A[(size_t)gr * K + gk + c];
                    v = make_float4(tv[0], tv[1], tv[2], tv[3]);
                }
            }
            unsigned short h0, l0, h1, l1, h2, l2, h3, l3;
            f2bf2(v.x, h0, l0); f2bf2(v.y, h1, l1);
            f2bf2(v.z, h2, l2); f2bf2(v.w, h3, l3);
            uint2 hv = make_uint2((unsigned)h0 | ((unsigned)h1 << 16),
                                  (unsigned)h2 | ((unsigned)h3 << 16));
            uint2 lv = make_uint2((unsigned)l0 | ((unsigned)l1 << 16),
                                  (unsigned)l2 | ((unsigned)l3 << 16));
            *(uint2*)&As_hi[r * ASTR2 + kq * 4] = hv;
            *(uint2*)&As_lo[r * ASTR2 + kq * 4] = lv;
        }
#pragma unroll
        for (int i = 0; i < 2; i++) {
            int idx = tid + i * 256;
            if (idx < 384) {
                int n = idx >> 2, kc = idx & 3;
                uint4 hv = *(const uint4*)(Bth + (size_t)n * KP + k0 + kc * 8);
                uint4 lv = *(const uint4*)(Btl + (size_t)n * KP + k0 + kc * 8);
                *(uint4*)&Bs_hi[n * ASTR2 + kc * 8] = hv;
                *(uint4*)&Bs_lo[n * ASTR2 + kc * 8] = lv;
            }
        }
        __syncthreads();

        bf16x8_t ah[2], al[2], bh[6], bl[6];
#pragma unroll
        for (int rt = 0; rt < 2; rt++) {
            int r = wid * 32 + rt * 16 + mn;
            ah[rt] = *(const bf16x8_t*)&As_hi[r * ASTR2 + q * 8];
            al[rt] = *(const bf16x8_t*)&As_lo[r * ASTR2 + q * 8];
        }
#pragma unroll
        for (int ct = 0; ct < 6; ct++) {
            int n = ct * 16 + mn;
            bh[ct] = *(const bf16x8_t*)&Bs_hi[n * ASTR2 + q * 8];
            bl[ct] = *(const bf16x8_t*)&Bs_lo[n * ASTR2 + q * 8];
        }
#pragma unroll
        for (int rt = 0; rt < 2; rt++)
#pragma unroll
            for (int ct = 0; ct < 6; ct++) {
                acc[rt][ct] = __builtin_amdgcn_mfma_f32_16x16x32_bf16(ah[rt], bh[ct], acc[rt][ct], 0, 0, 0);
                acc[rt][ct] = __builtin_amdgcn_mfma_f32_16x16x32_bf16(ah[rt], bl[ct], acc[rt][ct], 0, 0, 0);
                acc[rt][ct] = __builtin_amdgcn_mfma_f32_16x16x32_bf16(al[rt], bh[ct], acc[rt][ct], 0, 0, 0);
            }
        __syncthreads();
    }

#pragma unroll
    for (int rt = 0; rt < 2; rt++) {
#pragma unroll
        for (int reg = 0; reg < 4; reg++) {
            int gr = row0 + wid * 32 + rt * 16 + q * 4 + reg;
            if (gr < M) {
                size_t crow = ilv ? ((gr < ilv) ? (size_t)2 * gr : (size_t)2 * (gr - ilv) + 1)
                                  : (size_t)gr;
#pragma unroll
                for (int ct = 0; ct < 6; ct++)
                    C[crow * H96 + ct * 16 + mn] = acc[rt][ct][reg];
            }
        }
    }
}

// ---------------- build yz[i] = [no[i]*y[i] || no[i]*y[perm[i]]] (48 float4 per node) ----------------
__global__ void buildyz_kernel(const float4* __restrict__ y4, const int* __restrict__ perm,
                               const float* __restrict__ no, float4* __restrict__ yz, int N) {
    int idx = blockIdx.x * 256 + threadIdx.x;
    int i = idx / 48, q = idx - i * 48;
    if (i < N) {
        float s = no[i];
        float4 v;
        if (q < 24) v = y4[(size_t)i * 24 + q];
        else        v = y4[(size_t)perm[i] * 24 + (q - 24)];
        v.x *= s; v.y *= s; v.z *= s; v.w *= s;
        yz[(size_t)i * 48 + q] = v;
    }
}

// ---------------- helpers ----------------
__device__ __forceinline__ void fma4(float4& a, const float4& v) {
    a.x += v.x; a.y += v.y; a.z += v.z; a.w += v.w;
}

__device__ __forceinline__ float4 prelu4(float4 acc, float ni, float4 b, float4 a) {
    float4 h;
    h.x = fmaf(acc.x, ni, b.x); h.x = (h.x >= 0.f) ? h.x : a.x * h.x;
    h.y = fmaf(acc.y, ni, b.y); h.y = (h.y >= 0.f) ? h.y : a.y * h.y;
    h.z = fmaf(acc.z, ni, b.z); h.z = (h.z >= 0.f) ? h.z : a.z * h.z;
    h.w = fmaf(acc.w, ni, b.w); h.w = (h.w >= 0.f) ? h.w : a.w * h.w;
    return h;
}

// ---------------- layer-1 dual-view SpMM over interleaved table ----------------
// blockDim (24,16). Gathers yz[s] (768B): view1 half + view2 half, single index.
__global__ __launch_bounds__(384, 2) void spmm1_dual(
        const float4* __restrict__ yz, const int* __restrict__ row_start,
        const int* __restrict__ csr_src, const int* __restrict__ order,
        const float* __restrict__ norm_out, const float* __restrict__ norm_in,
        const float* __restrict__ b1, const float* __restrict__ a1,
        float4* __restrict__ h1, float4* __restrict__ h2, int N) {
    int g = blockIdx.x * 16 + threadIdx.y;
    if (g >= N) return;
    int d = order[g];
    int tx = threadIdx.x;
    int beg = row_start[d], end = row_start[d + 1];
    const float4* yt1 = yz + tx;
    const float4* yt2 = yz + 24 + tx;
    float4 acc1 = make_float4(0.f, 0.f, 0.f, 0.f);
    float4 acc2 = make_float4(0.f, 0.f, 0.f, 0.f);
    int j = beg;
    for (; j + 8 <= end; j += 8) {
        int s[8];
#pragma unroll
        for (int q = 0; q < 8; q++) s[q] = csr_src[j + q];
        float4 u[8], w[8];
#pragma unroll
        for (int q = 0; q < 8; q++) u[q] = yt1[(size_t)s[q] * 48];
#pragma unroll
        for (int q = 0; q < 8; q++) w[q] = yt2[(size_t)s[q] * 48];
#pragma unroll
        for (int q = 0; q < 8; q++) { fma4(acc1, u[q]); fma4(acc2, w[q]); }
    }
    for (; j < end; j++) {
        int s = csr_src[j];
        fma4(acc1, yt1[(size_t)s * 48]);
        fma4(acc2, yt2[(size_t)s * 48]);
    }
    float ni = norm_in[d], no = norm_out[d];
    float4 bb = ((const float4*)b1)[tx];
    float4 aa = ((const float4*)a1)[tx];
    float4 r1 = prelu4(acc1, ni, bb, aa);
    float4 r2 = prelu4(acc2, ni, bb, aa);
    r1.x *= no; r1.y *= no; r1.z *= no; r1.w *= no;
    r2.x *= no; r2.y *= no; r2.z *= no; r2.w *= no;
    h1[(size_t)d * 24 + tx] = r1;
    h2[(size_t)d * 24 + tx] = r2;
}

// ---------------- layer-2 dual-view SpMM over interleaved t + fused final dot ----------------
__global__ __launch_bounds__(384, 2) void spmm2_dual(
        const float4* __restrict__ tz,
        const int* __restrict__ row_start, const int* __restrict__ csr_src,
        const int* __restrict__ order, const float* __restrict__ norm_in,
        const float* __restrict__ b2, const float* __restrict__ a2,
        const float* __restrict__ wsum, const float* __restrict__ bsum,
        float* __restrict__ outp, int N) {
    int g = blockIdx.x * 16 + threadIdx.y;
    int tx = threadIdx.x;
    int ty = threadIdx.y;
    bool valid = (g < N);
    int d = valid ? order[g] : 0;
    int beg = 0, end = 0;
    if (valid) { beg = row_start[d]; end = row_start[d + 1]; }
    const float4* t1 = tz + tx;
    const float4* t2 = tz + 24 + tx;
    float4 acc1 = make_float4(0.f, 0.f, 0.f, 0.f);
    float4 acc2 = make_float4(0.f, 0.f, 0.f, 0.f);
    int j = beg;
    for (; j + 8 <= end; j += 8) {
        int s[8];
#pragma unroll
        for (int q = 0; q < 8; q++) s[q] = csr_src[j + q];
        float4 u[8], w[8];
#pragma unroll
        for (int q = 0; q < 8; q++) u[q] = t1[(size_t)s[q] * 48];
#pragma unroll
        for (int q = 0; q < 8; q++) w[q] = t2[(size_t)s[q] * 48];
#pragma unroll
        for (int q = 0; q < 8; q++) { fma4(acc1, u[q]); fma4(acc2, w[q]); }
    }
    for (; j < end; j++) {
        int s = csr_src[j];
        fma4(acc1, t1[(size_t)s * 48]);
        fma4(acc2, t2[(size_t)s * 48]);
    }
    float ni = valid ? norm_in[d] : 0.f;
    float4 bb = ((const float4*)b2)[tx];
    float4 aa = ((const float4*)a2)[tx];
    float4 wv = ((const float4*)wsum)[tx];
    float4 r1 = prelu4(acc1, ni, bb, aa);
    float4 r2 = prelu4(acc2, ni, bb, aa);
    float p1 = r1.x * wv.x + r1.y * wv.y + r1.z * wv.z + r1.w * wv.w;
    float p2 = r2.x * wv.x + r2.y * wv.y + r2.z * wv.z + r2.w * wv.w;
    __shared__ float red1[16][24];
    __shared__ float red2[16][24];
    red1[ty][tx] = p1;
    red2[ty][tx] = p2;
    __syncthreads();
    if (tx == 0 && valid) {
        float s1 = 0.f, s2 = 0.f;
#pragma unroll
        for (int k = 0; k < 24; k++) { s1 += red1[ty][k]; s2 += red2[ty][k]; }
        outp[d] = s1 + bsum[0];
        outp[N + d] = s2 + bsum[0];
    }
}

extern "C" void kernel_launch(void* const* d_in, const int* in_sizes, int n_in,
                              void* d_out, int out_size, void* d_ws, size_t ws_size,
                              hipStream_t stream) {
    const float* x    = (const float*)d_in[0];
    const int*   src  = (const int*)d_in[1];
    const int*   dst  = (const int*)d_in[2];
    const int*   perm = (const int*)d_in[3];
    const float* W1   = (const float*)d_in[4];
    const float* b1   = (const float*)d_in[5];
    const float* a1   = (const float*)d_in[6];
    const float* W2   = (const float*)d_in[7];
    const float* b2   = (const float*)d_in[8];
    const float* a2   = (const float*)d_in[9];
    const float* Wm   = (const float*)d_in[10];
    const float* bm   = (const float*)d_in[11];
    float* out = (float*)d_out;

    int E = in_sizes[1];
    int N = in_sizes[3];
    int F = in_sizes[0] / N;               // 500
    int KP1 = ((F + GBK - 1) / GBK) * GBK; // 512

    size_t NP = ((size_t)N + 256) & ~(size_t)255;
    size_t EP = ((size_t)E + 255) & ~(size_t)255;
    int nb = (N + 255) / 256;
    size_t HB = ((size_t)256 * nb + 255) & ~(size_t)255;

    int* deg_out   = (int*)d_ws;          // NP
    int* deg_in    = deg_out + NP;        // NP
    int* pre       = deg_in + NP;         // NP
    int* row_start = pre + NP;            // NP
    int* cursor    = row_start + NP;      // NP
    int* order     = cursor + NP;         // NP
    int* bsums     = order + NP;          // 256
    int* hb        = bsums + 256;         // HB
    int* hbs       = hb + HB;             // HB
    int* hpre      = hbs + HB;            // HB
    int* csr_src   = hpre + HB;           // EP
    float* norm_out = (float*)(csr_src + EP);  // NP
    float* norm_in  = norm_out + NP;           // NP
    float* wsum     = norm_in + NP;            // 128
    float* bsum     = wsum + 128;              // 128
    unsigned short* w1th = (unsigned short*)(bsum + 128); // 96*KP1 pad 49664
    unsigned short* w1tl = w1th + 49664;
    unsigned short* w2th = w1tl + 49664;                  // 96*96 pad 9728
    unsigned short* w2tl = w2th + 9728;
    float* y   = (float*)(w2tl + 9728);            // N*96
    float* yz  = y + (size_t)N * H96;              // 2N*96 (interleaved; later reused as tz)
    float* h1s = yz + (size_t)2 * N * H96;         // 2N*96
    float* tz  = yz;                               // reuse: yz dead after spmm1

    hipMemsetAsync(deg_out, 0, 2 * NP * sizeof(int), stream);
    deg_kernel<<<(E + 255) / 256, 256, 0, stream>>>(src, dst, deg_out, deg_in, E);
    norm_kernel<<<(N + 255) / 256, 256, 0, stream>>>(deg_out, deg_in, norm_out, norm_in, N);

    scanA_kernel<<<nb, 256, 0, stream>>>(deg_in, pre, bsums, N);
    scanB_kernel<<<1, 256, 0, stream>>>(bsums, nb);
    rowfin_kernel<<<nb, 256, 0, stream>>>(pre, bsums, row_start, cursor, N, E);
    scatter_kernel<<<(E + 255) / 256, 256, 0, stream>>>(src, dst, cursor, csr_src, E);

    histblk_kernel<<<nb, 256, 0, stream>>>(deg_in, hb, N, nb);
    int n2 = 256 * nb;
    int nb2 = (n2 + 255) / 256;
    scanA_kernel<<<nb2, 256, 0, stream>>>(hb, hpre, bsums, n2);
    scanB_kernel<<<1, 256, 0, stream>>>(bsums, nb2);
    scanC_kernel<<<nb2, 256, 0, stream>>>(hpre, bsums, hbs, n2);
    place_kernel<<<nb, 256, 0, stream>>>(deg_in, hbs, order, N, nb);

    wsum_kernel<<<1, 128, 0, stream>>>(Wm, bm, wsum, bsum);
    convB_kernel<<<(96 * KP1 + 255) / 256, 256, 0, stream>>>(W1, w1th, w1tl, F, KP1);
    convB_kernel<<<(96 * 96 + 255) / 256, 256, 0, stream>>>(W2, w2th, w2tl, H96, H96);

    // y = x @ W1 via bf16x3 MFMA
    gemm_mfma<<<(N + GBM - 1) / GBM, 256, 0, stream>>>(x, w1th, w1tl, y, N, F, KP1, 0);

    // yz[i] = [no[i]*y[i] || no[i]*y[perm[i]]]
    buildyz_kernel<<<((size_t)N * 48 + 255) / 256, 256, 0, stream>>>(
        (const float4*)y, perm, norm_out, (float4*)yz, N);

    int nsb = (N + 15) / 16;
    spmm1_dual<<<nsb, dim3(24, 16), 0, stream>>>(
        (const float4*)yz, row_start, csr_src, order, norm_out, norm_in,
        b1, a1, (float4*)h1s, (float4*)(h1s + (size_t)N * H96), N);

    // tz (view-interleaved) = h1s @ W2 via bf16x3 MFMA  (overwrites yz, dead now)
    gemm_mfma<<<(2 * N + GBM - 1) / GBM, 256, 0, stream>>>(h1s, w2th, w2tl, tz, 2 * N, H96, H96, N);

    spmm2_dual<<<nsb, dim3(24, 16), 0, stream>>>(
        (const float4*)tz, row_start, csr_src, order, norm_in, b2, a2,
        wsum, bsum, out, N);
}

// Round 10
// 533.475 us; speedup vs baseline: 1.0578x; 1.0578x over previous
//
#include <hip/hip_runtime.h>

#define H96 96

typedef __attribute__((ext_vector_type(8))) short bf16x8_t;
typedef __attribute__((ext_vector_type(4))) float f32x4_t;

// ---------------- degrees (int) ----------------
__global__ void deg_kernel(const int* __restrict__ src, const int* __restrict__ dst,
                           int* __restrict__ dout, int* __restrict__ din, int E) {
    int e = blockIdx.x * blockDim.x + threadIdx.x;
    if (e < E) {
        atomicAdd(dout + src[e], 1);
        atomicAdd(din + dst[e], 1);
    }
}

__global__ void norm_kernel(const int* __restrict__ dO, const int* __restrict__ dI,
                            float* __restrict__ no, float* __restrict__ ni, int N) {
    int i = blockIdx.x * blockDim.x + threadIdx.x;
    if (i < N) {
        no[i] = rsqrtf(fmaxf((float)dO[i], 1.0f));
        ni[i] = rsqrtf(fmaxf((float)dI[i], 1.0f));
    }
}

// ---------------- generic exclusive scan ----------------
__global__ void scanA_kernel(const int* __restrict__ in, int* __restrict__ pre,
                             int* __restrict__ bsums, int n) {
    __shared__ int s[256];
    int i = blockIdx.x * 256 + threadIdx.x;
    int v = (i < n) ? in[i] : 0;
    s[threadIdx.x] = v;
    __syncthreads();
    for (int off = 1; off < 256; off <<= 1) {
        int t = (threadIdx.x >= off) ? s[threadIdx.x - off] : 0;
        __syncthreads();
        s[threadIdx.x] += t;
        __syncthreads();
    }
    if (i < n) pre[i] = s[threadIdx.x] - v;
    if (threadIdx.x == 255) bsums[blockIdx.x] = s[255];
}

__global__ void scanB_kernel(int* __restrict__ bsums, int nb) {
    __shared__ int s[256];
    int v = (threadIdx.x < nb) ? bsums[threadIdx.x] : 0;
    s[threadIdx.x] = v;
    __syncthreads();
    for (int off = 1; off < 256; off <<= 1) {
        int t = (threadIdx.x >= off) ? s[threadIdx.x - off] : 0;
        __syncthreads();
        s[threadIdx.x] += t;
        __syncthreads();
    }
    if (threadIdx.x < nb) bsums[threadIdx.x] = s[threadIdx.x] - v;
}

__global__ void rowfin_kernel(const int* __restrict__ pre, const int* __restrict__ bsums,
                              int* __restrict__ row_start, int* __restrict__ cursor,
                              int N, int E) {
    int i = blockIdx.x * 256 + threadIdx.x;
    if (i < N) {
        int v = pre[i] + bsums[blockIdx.x];
        row_start[i] = v;
        cursor[i] = v;
    }
    if (i == 0) row_start[N] = E;
}

// CSR scatter: one packed 16B record per edge {src, perm[src], norm_out[src], 0}
__global__ void scatter_kernel(const int* __restrict__ src, const int* __restrict__ dst,
                               const int* __restrict__ perm, const float* __restrict__ norm_out,
                               int* __restrict__ cursor, int4* __restrict__ edge4, int E) {
    int e = blockIdx.x * 256 + threadIdx.x;
    if (e < E) {
        int d = dst[e];
        int s = src[e];
        int p = atomicAdd(cursor + d, 1);
        edge4[p] = make_int4(s, perm[s], __float_as_int(norm_out[s]), 0);
    }
}

// ---------------- low-contention counting sort by deg_in ----------------
__global__ void histblk_kernel(const int* __restrict__ deg, int* __restrict__ hb,
                               int N, int nb) {
    __shared__ int h[256];
    h[threadIdx.x] = 0;
    __syncthreads();
    int i = blockIdx.x * 256 + threadIdx.x;
    if (i < N) atomicAdd(&h[min(deg[i], 255)], 1);
    __syncthreads();
    hb[threadIdx.x * nb + blockIdx.x] = h[threadIdx.x];
}

// place with inline hbs = hpre + bsums  (fuses old scanC)
__global__ void place2_kernel(const int* __restrict__ deg, const int* __restrict__ hpre,
                              const int* __restrict__ bsums, int* __restrict__ order,
                              int N, int nb) {
    __shared__ int cur[256];
    int idx = threadIdx.x * nb + blockIdx.x;
    cur[threadIdx.x] = hpre[idx] + bsums[idx >> 8];
    __syncthreads();
    int i = blockIdx.x * 256 + threadIdx.x;
    if (i < N) {
        int b = min(deg[i], 255);
        int p = atomicAdd(&cur[b], 1);
        order[p] = i;
    }
}

// ---------------- bf16 hi/lo split helper ----------------
__device__ __forceinline__ void f2bf2(float v, unsigned short& h, unsigned short& l) {
    unsigned int b = __float_as_uint(v);
    unsigned short hh = (unsigned short)((b + 0x7FFFu + ((b >> 16) & 1u)) >> 16);
    float fh = __uint_as_float(((unsigned int)hh) << 16);
    float r = v - fh;
    unsigned int rb = __float_as_uint(r);
    unsigned short ll = (unsigned short)((rb + 0x7FFFu + ((rb >> 16) & 1u)) >> 16);
    h = hh; l = ll;
}

// fused weights prep: W1 transpose/split, W2 transpose/split, wsum, bsum
__global__ void weights_prep(const float* __restrict__ W1, const float* __restrict__ W2,
                             const float* __restrict__ Wm, const float* __restrict__ bm,
                             unsigned short* __restrict__ w1h, unsigned short* __restrict__ w1l,
                             unsigned short* __restrict__ w2h, unsigned short* __restrict__ w2l,
                             float* __restrict__ wsum, float* __restrict__ bsum,
                             int F, int KP1) {
    int idx = blockIdx.x * 256 + threadIdx.x;
    int z1 = 96 * KP1, z2 = z1 + 96 * 96;
    if (idx < z1) {
        int n = idx / KP1, k = idx - n * KP1;
        float v = (k < F) ? W1[(size_t)k * 96 + n] : 0.f;
        unsigned short h, l;
        f2bf2(v, h, l);
        w1h[idx] = h; w1l[idx] = l;
    } else if (idx < z2) {
        int t = idx - z1;
        int n = t / 96, k = t - n * 96;
        float v = W2[(size_t)k * 96 + n];
        unsigned short h, l;
        f2bf2(v, h, l);
        w2h[t] = h; w2l[t] = l;
    } else if (idx < z2 + 96) {
        int c = idx - z2;
        float s = 0.f;
        for (int j = 0; j < 96; j++) s += Wm[c * 96 + j];
        wsum[c] = s;
    } else if (idx == z2 + 96) {
        float s = 0.f;
        for (int j = 0; j < 96; j++) s += bm[j];
        bsum[0] = s;
    }
}

// ---------------- bf16x3 MFMA GEMM: C[M,96] = A[M,K] @ B[K,96] ----------------
#define GBM 128
#define GBK 32
#define ASTR2 40
__global__ __launch_bounds__(256) void gemm_mfma(const float* __restrict__ A,
                                                 const unsigned short* __restrict__ Bth,
                                                 const unsigned short* __restrict__ Btl,
                                                 float* __restrict__ C, int M, int K, int KP) {
    __shared__ unsigned short As_hi[GBM * ASTR2];
    __shared__ unsigned short As_lo[GBM * ASTR2];
    __shared__ unsigned short Bs_hi[96 * ASTR2];
    __shared__ unsigned short Bs_lo[96 * ASTR2];
    int tid = threadIdx.x;
    int row0 = blockIdx.x * GBM;
    int wid = tid >> 6, lane = tid & 63;
    int q = lane >> 4, mn = lane & 15;
    f32x4_t acc[2][6] = {};
    int nk = (K + GBK - 1) / GBK;

    for (int t = 0; t < nk; t++) {
        int k0 = t * GBK;
#pragma unroll
        for (int i = 0; i < 4; i++) {
            int idx = tid + i * 256;
            int r = idx >> 3, kq = idx & 7;
            int gr = row0 + r, gk = k0 + kq * 4;
            float4 v = make_float4(0.f, 0.f, 0.f, 0.f);
            if (gr < M) {
                if (gk + 4 <= K) {
                    v = *(const float4*)(A + (size_t)gr * K + gk);
                } else {
                    float tv[4] = {0.f, 0.f, 0.f, 0.f};
                    for (int c = 0; c < 4; c++)
                        if (gk + c < K) tv[c] = A[(size_t)gr * K + gk + c];
                    v = make_float4(tv[0], tv[1], tv[2], tv[3]);
                }
            }
            unsigned short h0, l0, h1, l1, h2, l2, h3, l3;
            f2bf2(v.x, h0, l0); f2bf2(v.y, h1, l1);
            f2bf2(v.z, h2, l2); f2bf2(v.w, h3, l3);
            uint2 hv = make_uint2((unsigned)h0 | ((unsigned)h1 << 16),
                                  (unsigned)h2 | ((unsigned)h3 << 16));
            uint2 lv = make_uint2((unsigned)l0 | ((unsigned)l1 << 16),
                                  (unsigned)l2 | ((unsigned)l3 << 16));
            *(uint2*)&As_hi[r * ASTR2 + kq * 4] = hv;
            *(uint2*)&As_lo[r * ASTR2 + kq * 4] = lv;
        }
#pragma unroll
        for (int i = 0; i < 2; i++) {
            int idx = tid + i * 256;
            if (idx < 384) {
                int n = idx >> 2, kc = idx & 3;
                uint4 hv = *(const uint4*)(Bth + (size_t)n * KP + k0 + kc * 8);
                uint4 lv = *(const uint4*)(Btl + (size_t)n * KP + k0 + kc * 8);
                *(uint4*)&Bs_hi[n * ASTR2 + kc * 8] = hv;
                *(uint4*)&Bs_lo[n * ASTR2 + kc * 8] = lv;
            }
        }
        __syncthreads();

        bf16x8_t ah[2], al[2], bh[6], bl[6];
#pragma unroll
        for (int rt = 0; rt < 2; rt++) {
            int r = wid * 32 + rt * 16 + mn;
            ah[rt] = *(const bf16x8_t*)&As_hi[r * ASTR2 + q * 8];
            al[rt] = *(const bf16x8_t*)&As_lo[r * ASTR2 + q * 8];
        }
#pragma unroll
        for (int ct = 0; ct < 6; ct++) {
            int n = ct * 16 + mn;
            bh[ct] = *(const bf16x8_t*)&Bs_hi[n * ASTR2 + q * 8];
            bl[ct] = *(const bf16x8_t*)&Bs_lo[n * ASTR2 + q * 8];
        }
#pragma unroll
        for (int rt = 0; rt < 2; rt++)
#pragma unroll
            for (int ct = 0; ct < 6; ct++) {
                acc[rt][ct] = __builtin_amdgcn_mfma_f32_16x16x32_bf16(ah[rt], bh[ct], acc[rt][ct], 0, 0, 0);
                acc[rt][ct] = __builtin_amdgcn_mfma_f32_16x16x32_bf16(ah[rt], bl[ct], acc[rt][ct], 0, 0, 0);
                acc[rt][ct] = __builtin_amdgcn_mfma_f32_16x16x32_bf16(al[rt], bh[ct], acc[rt][ct], 0, 0, 0);
            }
        __syncthreads();
    }

#pragma unroll
    for (int rt = 0; rt < 2; rt++) {
#pragma unroll
        for (int reg = 0; reg < 4; reg++) {
            int gr = row0 + wid * 32 + rt * 16 + q * 4 + reg;
            if (gr < M) {
#pragma unroll
                for (int ct = 0; ct < 6; ct++)
                    C[(size_t)gr * H96 + ct * 16 + mn] = acc[rt][ct][reg];
            }
        }
    }
}

// ---------------- helpers ----------------
__device__ __forceinline__ void fma4s(float4& a, float s, const float4& v) {
    a.x = fmaf(s, v.x, a.x);
    a.y = fmaf(s, v.y, a.y);
    a.z = fmaf(s, v.z, a.z);
    a.w = fmaf(s, v.w, a.w);
}

__device__ __forceinline__ void add4(float4& a, const float4& v) {
    a.x += v.x; a.y += v.y; a.z += v.z; a.w += v.w;
}

__device__ __forceinline__ float4 prelu4(float4 acc, float ni, float4 b, float4 a) {
    float4 h;
    h.x = fmaf(acc.x, ni, b.x); h.x = (h.x >= 0.f) ? h.x : a.x * h.x;
    h.y = fmaf(acc.y, ni, b.y); h.y = (h.y >= 0.f) ? h.y : a.y * h.y;
    h.z = fmaf(acc.z, ni, b.z); h.z = (h.z >= 0.f) ? h.z : a.z * h.z;
    h.w = fmaf(acc.w, ni, b.w); h.w = (h.w >= 0.f) ? h.w : a.w * h.w;
    return h;
}

// ---------------- layer-1 dual-view SpMM: packed edges, y table 19.2MB ----------------
__global__ __launch_bounds__(384) void spmm1_dual(
        const float4* __restrict__ y4, const int* __restrict__ row_start,
        const int4* __restrict__ edge4, const int* __restrict__ order,
        const float* __restrict__ norm_out, const float* __restrict__ norm_in,
        const float* __restrict__ b1, const float* __restrict__ a1,
        float4* __restrict__ h1, float4* __restrict__ h2, int N) {
    int g = blockIdx.x * 16 + threadIdx.y;
    if (g >= N) return;
    int d = order[g];
    int tx = threadIdx.x;
    int beg = row_start[d], end = row_start[d + 1];
    const float4* yt = y4 + tx;
    float4 acc1 = make_float4(0.f, 0.f, 0.f, 0.f);
    float4 acc2 = make_float4(0.f, 0.f, 0.f, 0.f);
    int j = beg;
    for (; j + 8 <= end; j += 8) {
        int4 e[8];
#pragma unroll
        for (int q = 0; q < 8; q++) e[q] = edge4[j + q];
        float4 u[8], w[8];
#pragma unroll
        for (int q = 0; q < 8; q++) u[q] = yt[(size_t)e[q].x * 24];
#pragma unroll
        for (int q = 0; q < 8; q++) w[q] = yt[(size_t)e[q].y * 24];
#pragma unroll
        for (int q = 0; q < 8; q++) {
            float n = __int_as_float(e[q].z);
            fma4s(acc1, n, u[q]);
            fma4s(acc2, n, w[q]);
        }
    }
    for (; j < end; j++) {
        int4 e = edge4[j];
        float n = __int_as_float(e.z);
        fma4s(acc1, n, yt[(size_t)e.x * 24]);
        fma4s(acc2, n, yt[(size_t)e.y * 24]);
    }
    float ni = norm_in[d], no = norm_out[d];
    float4 bb = ((const float4*)b1)[tx];
    float4 aa = ((const float4*)a1)[tx];
    float4 r1 = prelu4(acc1, ni, bb, aa);
    float4 r2 = prelu4(acc2, ni, bb, aa);
    r1.x *= no; r1.y *= no; r1.z *= no; r1.w *= no;
    r2.x *= no; r2.y *= no; r2.z *= no; r2.w *= no;
    h1[(size_t)d * 24 + tx] = r1;
    h2[(size_t)d * 24 + tx] = r2;
}

// ---------------- layer-2 dual-view SpMM + fused final dot ----------------
__global__ __launch_bounds__(384) void spmm2_dual(
        const float4* __restrict__ t4,
        const int* __restrict__ row_start, const int4* __restrict__ edge4,
        const int* __restrict__ order, const float* __restrict__ norm_in,
        const float* __restrict__ b2, const float* __restrict__ a2,
        const float* __restrict__ wsum, const float* __restrict__ bsum,
        float* __restrict__ outp, int N) {
    int g = blockIdx.x * 16 + threadIdx.y;
    int tx = threadIdx.x;
    int ty = threadIdx.y;
    bool valid = (g < N);
    int d = valid ? order[g] : 0;
    int beg = 0, end = 0;
    if (valid) { beg = row_start[d]; end = row_start[d + 1]; }
    const float4* t1 = t4 + tx;
    const float4* t2 = t4 + (size_t)N * 24 + tx;
    float4 acc1 = make_float4(0.f, 0.f, 0.f, 0.f);
    float4 acc2 = make_float4(0.f, 0.f, 0.f, 0.f);
    int j = beg;
    for (; j + 8 <= end; j += 8) {
        int s[8];
#pragma unroll
        for (int q = 0; q < 8; q++) s[q] = edge4[j + q].x;
        float4 u[8], w[8];
#pragma unroll
        for (int q = 0; q < 8; q++) u[q] = t1[(size_t)s[q] * 24];
#pragma unroll
        for (int q = 0; q < 8; q++) w[q] = t2[(size_t)s[q] * 24];
#pragma unroll
        for (int q = 0; q < 8; q++) { add4(acc1, u[q]); add4(acc2, w[q]); }
    }
    for (; j < end; j++) {
        int s = edge4[j].x;
        add4(acc1, t1[(size_t)s * 24]);
        add4(acc2, t2[(size_t)s * 24]);
    }
    float ni = valid ? norm_in[d] : 0.f;
    float4 bb = ((const float4*)b2)[tx];
    float4 aa = ((const float4*)a2)[tx];
    float4 wv = ((const float4*)wsum)[tx];
    float4 r1 = prelu4(acc1, ni, bb, aa);
    float4 r2 = prelu4(acc2, ni, bb, aa);
    float p1 = r1.x * wv.x + r1.y * wv.y + r1.z * wv.z + r1.w * wv.w;
    float p2 = r2.x * wv.x + r2.y * wv.y + r2.z * wv.z + r2.w * wv.w;
    __shared__ float red1[16][24];
    __shared__ float red2[16][24];
    red1[ty][tx] = p1;
    red2[ty][tx] = p2;
    __syncthreads();
    if (tx == 0 && valid) {
        float s1 = 0.f, s2 = 0.f;
#pragma unroll
        for (int k = 0; k < 24; k++) { s1 += red1[ty][k]; s2 += red2[ty][k]; }
        outp[d] = s1 + bsum[0];
        outp[N + d] = s2 + bsum[0];
    }
}

extern "C" void kernel_launch(void* const* d_in, const int* in_sizes, int n_in,
                              void* d_out, int out_size, void* d_ws, size_t ws_size,
                              hipStream_t stream) {
    const float* x    = (const float*)d_in[0];
    const int*   src  = (const int*)d_in[1];
    const int*   dst  = (const int*)d_in[2];
    const int*   perm = (const int*)d_in[3];
    const float* W1   = (const float*)d_in[4];
    const float* b1   = (const float*)d_in[5];
    const float* a1   = (const float*)d_in[6];
    const float* W2   = (const float*)d_in[7];
    const float* b2   = (const float*)d_in[8];
    const float* a2   = (const float*)d_in[9];
    const float* Wm   = (const float*)d_in[10];
    const float* bm   = (const float*)d_in[11];
    float* out = (float*)d_out;

    int E = in_sizes[1];
    int N = in_sizes[3];
    int F = in_sizes[0] / N;               // 500
    int KP1 = ((F + GBK - 1) / GBK) * GBK; // 512

    size_t NP = ((size_t)N + 256) & ~(size_t)255;
    size_t EP = ((size_t)E + 255) & ~(size_t)255;
    int nb = (N + 255) / 256;
    size_t HB = ((size_t)256 * nb + 255) & ~(size_t)255;

    int* deg_out   = (int*)d_ws;          // NP
    int* deg_in    = deg_out + NP;        // NP
    int* pre       = deg_in + NP;         // NP
    int* row_start = pre + NP;            // NP
    int* cursor    = row_start + NP;      // NP
    int* order     = cursor + NP;         // NP
    int* bsums     = order + NP;          // 256
    int* hb        = bsums + 256;         // HB
    int* hpre      = hb + HB;             // HB
    int4* edge4    = (int4*)(hpre + HB);  // EP int4 (16B each)
    float* norm_out = (float*)(edge4 + EP);    // NP
    float* norm_in  = norm_out + NP;           // NP
    float* wsum     = norm_in + NP;            // 128
    float* bsum     = wsum + 128;              // 128
    unsigned short* w1th = (unsigned short*)(bsum + 128); // 96*KP1 pad 49664
    unsigned short* w1tl = w1th + 49664;
    unsigned short* w2th = w1tl + 49664;                  // 96*96 pad 9728
    unsigned short* w2tl = w2th + 9728;
    float* tbuf = (float*)(w2tl + 9728);           // 2N*96 (first N*96 doubles as y)
    float* h1s  = tbuf + (size_t)2 * N * H96;      // 2N*96

    hipMemsetAsync(deg_out, 0, 2 * NP * sizeof(int), stream);
    deg_kernel<<<(E + 255) / 256, 256, 0, stream>>>(src, dst, deg_out, deg_in, E);
    norm_kernel<<<(N + 255) / 256, 256, 0, stream>>>(deg_out, deg_in, norm_out, norm_in, N);

    scanA_kernel<<<nb, 256, 0, stream>>>(deg_in, pre, bsums, N);
    scanB_kernel<<<1, 256, 0, stream>>>(bsums, nb);
    rowfin_kernel<<<nb, 256, 0, stream>>>(pre, bsums, row_start, cursor, N, E);
    scatter_kernel<<<(E + 255) / 256, 256, 0, stream>>>(src, dst, perm, norm_out, cursor,
                                                        edge4, E);

    histblk_kernel<<<nb, 256, 0, stream>>>(deg_in, hb, N, nb);
    int n2 = 256 * nb;
    int nb2 = (n2 + 255) / 256;
    scanA_kernel<<<nb2, 256, 0, stream>>>(hb, hpre, bsums, n2);
    scanB_kernel<<<1, 256, 0, stream>>>(bsums, nb2);
    place2_kernel<<<nb, 256, 0, stream>>>(deg_in, hpre, bsums, order, N, nb);

    int wtot = 96 * KP1 + 96 * 96 + 96 + 1;
    weights_prep<<<(wtot + 255) / 256, 256, 0, stream>>>(W1, W2, Wm, bm, w1th, w1tl,
                                                         w2th, w2tl, wsum, bsum, F, KP1);

    float* y = tbuf;  // reuse: y dead before tbuf is written
    // y = x @ W1 via bf16x3 MFMA
    gemm_mfma<<<(N + GBM - 1) / GBM, 256, 0, stream>>>(x, w1th, w1tl, y, N, F, KP1);

    int nsb = (N + 15) / 16;
    spmm1_dual<<<nsb, dim3(24, 16), 0, stream>>>(
        (const float4*)y, row_start, edge4, order, norm_out, norm_in,
        b1, a1, (float4*)h1s, (float4*)(h1s + (size_t)N * H96), N);

    // tbuf[2N,96] = h1s @ W2 via bf16x3 MFMA (overwrites y, dead now)
    gemm_mfma<<<(2 * N + GBM - 1) / GBM, 256, 0, stream>>>(h1s, w2th, w2tl, tbuf, 2 * N, H96, H96);

    spmm2_dual<<<nsb, dim3(24, 16), 0, stream>>>(
        (const float4*)tbuf, row_start, edge4, order, norm_in, b2, a2,
        wsum, bsum, out, N);
}

// Round 11
// 469.931 us; speedup vs baseline: 1.2008x; 1.1352x over previous
//
#include <hip/hip_runtime.h>

#define H96 96

typedef __attribute__((ext_vector_type(8))) short bf16x8_t;
typedef __attribute__((ext_vector_type(4))) float f32x4_t;
typedef __attribute__((ext_vector_type(8))) _Float16 half8_t;

// ---------------- degrees (int) ----------------
__global__ void deg_kernel(const int* __restrict__ src, const int* __restrict__ dst,
                           int* __restrict__ dout, int* __restrict__ din, int E) {
    int e = blockIdx.x * blockDim.x + threadIdx.x;
    if (e < E) {
        atomicAdd(dout + src[e], 1);
        atomicAdd(din + dst[e], 1);
    }
}

__global__ void norm_kernel(const int* __restrict__ dO, const int* __restrict__ dI,
                            float* __restrict__ no, float* __restrict__ ni, int N) {
    int i = blockIdx.x * blockDim.x + threadIdx.x;
    if (i < N) {
        no[i] = rsqrtf(fmaxf((float)dO[i], 1.0f));
        ni[i] = rsqrtf(fmaxf((float)dI[i], 1.0f));
    }
}

// ---------------- generic exclusive scan ----------------
__global__ void scanA_kernel(const int* __restrict__ in, int* __restrict__ pre,
                             int* __restrict__ bsums, int n) {
    __shared__ int s[256];
    int i = blockIdx.x * 256 + threadIdx.x;
    int v = (i < n) ? in[i] : 0;
    s[threadIdx.x] = v;
    __syncthreads();
    for (int off = 1; off < 256; off <<= 1) {
        int t = (threadIdx.x >= off) ? s[threadIdx.x - off] : 0;
        __syncthreads();
        s[threadIdx.x] += t;
        __syncthreads();
    }
    if (i < n) pre[i] = s[threadIdx.x] - v;
    if (threadIdx.x == 255) bsums[blockIdx.x] = s[255];
}

__global__ void scanB_kernel(int* __restrict__ bsums, int nb) {
    __shared__ int s[256];
    int v = (threadIdx.x < nb) ? bsums[threadIdx.x] : 0;
    s[threadIdx.x] = v;
    __syncthreads();
    for (int off = 1; off < 256; off <<= 1) {
        int t = (threadIdx.x >= off) ? s[threadIdx.x - off] : 0;
        __syncthreads();
        s[threadIdx.x] += t;
        __syncthreads();
    }
    if (threadIdx.x < nb) bsums[threadIdx.x] = s[threadIdx.x] - v;
}

__global__ void rowfin_kernel(const int* __restrict__ pre, const int* __restrict__ bsums,
                              int* __restrict__ row_start, int* __restrict__ cursor,
                              int N, int E) {
    int i = blockIdx.x * 256 + threadIdx.x;
    if (i < N) {
        int v = pre[i] + bsums[blockIdx.x];
        row_start[i] = v;
        cursor[i] = v;
    }
    if (i == 0) row_start[N] = E;
}

// CSR scatter: packed 16B record per edge {src, perm[src], norm_out[src], 0}
__global__ void scatter_kernel(const int* __restrict__ src, const int* __restrict__ dst,
                               const int* __restrict__ perm, const float* __restrict__ norm_out,
                               int* __restrict__ cursor, int4* __restrict__ edge4, int E) {
    int e = blockIdx.x * 256 + threadIdx.x;
    if (e < E) {
        int d = dst[e];
        int s = src[e];
        int p = atomicAdd(cursor + d, 1);
        edge4[p] = make_int4(s, perm[s], __float_as_int(norm_out[s]), 0);
    }
}

// ---------------- low-contention counting sort by deg_in ----------------
__global__ void histblk_kernel(const int* __restrict__ deg, int* __restrict__ hb,
                               int N, int nb) {
    __shared__ int h[256];
    h[threadIdx.x] = 0;
    __syncthreads();
    int i = blockIdx.x * 256 + threadIdx.x;
    if (i < N) atomicAdd(&h[min(deg[i], 255)], 1);
    __syncthreads();
    hb[threadIdx.x * nb + blockIdx.x] = h[threadIdx.x];
}

__global__ void place2_kernel(const int* __restrict__ deg, const int* __restrict__ hpre,
                              const int* __restrict__ bsums, int* __restrict__ order,
                              int N, int nb) {
    __shared__ int cur[256];
    int idx = threadIdx.x * nb + blockIdx.x;
    cur[threadIdx.x] = hpre[idx] + bsums[idx >> 8];
    __syncthreads();
    int i = blockIdx.x * 256 + threadIdx.x;
    if (i < N) {
        int b = min(deg[i], 255);
        int p = atomicAdd(&cur[b], 1);
        order[p] = i;
    }
}

// ---------------- bf16 hi/lo split helper ----------------
__device__ __forceinline__ void f2bf2(float v, unsigned short& h, unsigned short& l) {
    unsigned int b = __float_as_uint(v);
    unsigned short hh = (unsigned short)((b + 0x7FFFu + ((b >> 16) & 1u)) >> 16);
    float fh = __uint_as_float(((unsigned int)hh) << 16);
    float r = v - fh;
    unsigned int rb = __float_as_uint(r);
    unsigned short ll = (unsigned short)((rb + 0x7FFFu + ((rb >> 16) & 1u)) >> 16);
    h = hh; l = ll;
}

// fused weights prep
__global__ void weights_prep(const float* __restrict__ W1, const float* __restrict__ W2,
                             const float* __restrict__ Wm, const float* __restrict__ bm,
                             unsigned short* __restrict__ w1h, unsigned short* __restrict__ w1l,
                             unsigned short* __restrict__ w2h, unsigned short* __restrict__ w2l,
                             float* __restrict__ wsum, float* __restrict__ bsum,
                             int F, int KP1) {
    int idx = blockIdx.x * 256 + threadIdx.x;
    int z1 = 96 * KP1, z2 = z1 + 96 * 96;
    if (idx < z1) {
        int n = idx / KP1, k = idx - n * KP1;
        float v = (k < F) ? W1[(size_t)k * 96 + n] : 0.f;
        unsigned short h, l;
        f2bf2(v, h, l);
        w1h[idx] = h; w1l[idx] = l;
    } else if (idx < z2) {
        int t = idx - z1;
        int n = t / 96, k = t - n * 96;
        float v = W2[(size_t)k * 96 + n];
        unsigned short h, l;
        f2bf2(v, h, l);
        w2h[t] = h; w2l[t] = l;
    } else if (idx < z2 + 96) {
        int c = idx - z2;
        float s = 0.f;
        for (int j = 0; j < 96; j++) s += Wm[c * 96 + j];
        wsum[c] = s;
    } else if (idx == z2 + 96) {
        float s = 0.f;
        for (int j = 0; j < 96; j++) s += bm[j];
        bsum[0] = s;
    }
}

// ---------------- bf16x3 MFMA GEMM: C16[M,96] (fp16) = A[M,K] @ B[K,96] ----------------
#define GBM 128
#define GBK 32
#define ASTR2 40
__global__ __launch_bounds__(256) void gemm_mfma(const float* __restrict__ A,
                                                 const unsigned short* __restrict__ Bth,
                                                 const unsigned short* __restrict__ Btl,
                                                 _Float16* __restrict__ C16,
                                                 int M, int K, int KP) {
    __shared__ unsigned short As_hi[GBM * ASTR2];
    __shared__ unsigned short As_lo[GBM * ASTR2];
    __shared__ unsigned short Bs_hi[96 * ASTR2];
    __shared__ unsigned short Bs_lo[96 * ASTR2];
    int tid = threadIdx.x;
    int row0 = blockIdx.x * GBM;
    int wid = tid >> 6, lane = tid & 63;
    int q = lane >> 4, mn = lane & 15;
    f32x4_t acc[2][6] = {};
    int nk = (K + GBK - 1) / GBK;

    for (int t = 0; t < nk; t++) {
        int k0 = t * GBK;
#pragma unroll
        for (int i = 0; i < 4; i++) {
            int idx = tid + i * 256;
            int r = idx >> 3, kq = idx & 7;
            int gr = row0 + r, gk = k0 + kq * 4;
            float4 v = make_float4(0.f, 0.f, 0.f, 0.f);
            if (gr < M) {
                if (gk + 4 <= K) {
                    v = *(const float4*)(A + (size_t)gr * K + gk);
                } else {
                    float tv[4] = {0.f, 0.f, 0.f, 0.f};
                    for (int c = 0; c < 4; c++)
                        if (gk + c < K) tv[c] = A[(size_t)gr * K + gk + c];
                    v = make_float4(tv[0], tv[1], tv[2], tv[3]);
                }
            }
            unsigned short h0, l0, h1, l1, h2, l2, h3, l3;
            f2bf2(v.x, h0, l0); f2bf2(v.y, h1, l1);
            f2bf2(v.z, h2, l2); f2bf2(v.w, h3, l3);
            uint2 hv = make_uint2((unsigned)h0 | ((unsigned)h1 << 16),
                                  (unsigned)h2 | ((unsigned)h3 << 16));
            uint2 lv = make_uint2((unsigned)l0 | ((unsigned)l1 << 16),
                                  (unsigned)l2 | ((unsigned)l3 << 16));
            *(uint2*)&As_hi[r * ASTR2 + kq * 4] = hv;
            *(uint2*)&As_lo[r * ASTR2 + kq * 4] = lv;
        }
#pragma unroll
        for (int i = 0; i < 2; i++) {
            int idx = tid + i * 256;
            if (idx < 384) {
                int n = idx >> 2, kc = idx & 3;
                uint4 hv = *(const uint4*)(Bth + (size_t)n * KP + k0 + kc * 8);
                uint4 lv = *(const uint4*)(Btl + (size_t)n * KP + k0 + kc * 8);
                *(uint4*)&Bs_hi[n * ASTR2 + kc * 8] = hv;
                *(uint4*)&Bs_lo[n * ASTR2 + kc * 8] = lv;
            }
        }
        __syncthreads();

        bf16x8_t ah[2], al[2], bh[6], bl[6];
#pragma unroll
        for (int rt = 0; rt < 2; rt++) {
            int r = wid * 32 + rt * 16 + mn;
            ah[rt] = *(const bf16x8_t*)&As_hi[r * ASTR2 + q * 8];
            al[rt] = *(const bf16x8_t*)&As_lo[r * ASTR2 + q * 8];
        }
#pragma unroll
        for (int ct = 0; ct < 6; ct++) {
            int n = ct * 16 + mn;
            bh[ct] = *(const bf16x8_t*)&Bs_hi[n * ASTR2 + q * 8];
            bl[ct] = *(const bf16x8_t*)&Bs_lo[n * ASTR2 + q * 8];
        }
#pragma unroll
        for (int rt = 0; rt < 2; rt++)
#pragma unroll
            for (int ct = 0; ct < 6; ct++) {
                acc[rt][ct] = __builtin_amdgcn_mfma_f32_16x16x32_bf16(ah[rt], bh[ct], acc[rt][ct], 0, 0, 0);
                acc[rt][ct] = __builtin_amdgcn_mfma_f32_16x16x32_bf16(ah[rt], bl[ct], acc[rt][ct], 0, 0, 0);
                acc[rt][ct] = __builtin_amdgcn_mfma_f32_16x16x32_bf16(al[rt], bh[ct], acc[rt][ct], 0, 0, 0);
            }
        __syncthreads();
    }

#pragma unroll
    for (int rt = 0; rt < 2; rt++) {
#pragma unroll
        for (int reg = 0; reg < 4; reg++) {
            int gr = row0 + wid * 32 + rt * 16 + q * 4 + reg;
            if (gr < M) {
#pragma unroll
                for (int ct = 0; ct < 6; ct++)
                    C16[(size_t)gr * H96 + ct * 16 + mn] = (_Float16)acc[rt][ct][reg];
            }
        }
    }
}

// ---------------- helpers ----------------
__device__ __forceinline__ void fmah8(float4& a, float4& b, float s, half8_t v) {
    a.x = fmaf(s, (float)v[0], a.x); a.y = fmaf(s, (float)v[1], a.y);
    a.z = fmaf(s, (float)v[2], a.z); a.w = fmaf(s, (float)v[3], a.w);
    b.x = fmaf(s, (float)v[4], b.x); b.y = fmaf(s, (float)v[5], b.y);
    b.z = fmaf(s, (float)v[6], b.z); b.w = fmaf(s, (float)v[7], b.w);
}

__device__ __forceinline__ float4 prelu4(float4 acc, float ni, float4 b, float4 a) {
    float4 h;
    h.x = fmaf(acc.x, ni, b.x); h.x = (h.x >= 0.f) ? h.x : a.x * h.x;
    h.y = fmaf(acc.y, ni, b.y); h.y = (h.y >= 0.f) ? h.y : a.y * h.y;
    h.z = fmaf(acc.z, ni, b.z); h.z = (h.z >= 0.f) ? h.z : a.z * h.z;
    h.w = fmaf(acc.w, ni, b.w); h.w = (h.w >= 0.f) ? h.w : a.w * h.w;
    return h;
}

// ---------------- layer-1 dual-view SpMM over fp16 y table ----------------
// blockDim (12,32): 12 lanes x half8 (16B) cover a 192B row.
__global__ __launch_bounds__(384) void spmm1_dual(
        const half8_t* __restrict__ yh, const int* __restrict__ row_start,
        const int4* __restrict__ edge4, const int* __restrict__ order,
        const float* __restrict__ norm_out, const float* __restrict__ norm_in,
        const float* __restrict__ b1, const float* __restrict__ a1,
        float4* __restrict__ h1, float4* __restrict__ h2, int N) {
    int g = blockIdx.x * 32 + threadIdx.y;
    if (g >= N) return;
    int d = order[g];
    int tx = threadIdx.x;
    int beg = row_start[d], end = row_start[d + 1];
    const half8_t* yt = yh + tx;
    float4 a1a = {0,0,0,0}, a1b = {0,0,0,0}, a2a = {0,0,0,0}, a2b = {0,0,0,0};
    int j = beg;
    for (; j + 8 <= end; j += 8) {
        int4 e[8];
#pragma unroll
        for (int q = 0; q < 8; q++) e[q] = edge4[j + q];
        half8_t u[8], w[8];
#pragma unroll
        for (int q = 0; q < 8; q++) u[q] = yt[(size_t)e[q].x * 12];
#pragma unroll
        for (int q = 0; q < 8; q++) w[q] = yt[(size_t)e[q].y * 12];
#pragma unroll
        for (int q = 0; q < 8; q++) {
            float n = __int_as_float(e[q].z);
            fmah8(a1a, a1b, n, u[q]);
            fmah8(a2a, a2b, n, w[q]);
        }
    }
    for (; j < end; j++) {
        int4 e = edge4[j];
        float n = __int_as_float(e.z);
        fmah8(a1a, a1b, n, yt[(size_t)e.x * 12]);
        fmah8(a2a, a2b, n, yt[(size_t)e.y * 12]);
    }
    float ni = norm_in[d], no = norm_out[d];
    float4 bb0 = ((const float4*)b1)[tx * 2], bb1 = ((const float4*)b1)[tx * 2 + 1];
    float4 aa0 = ((const float4*)a1)[tx * 2], aa1 = ((const float4*)a1)[tx * 2 + 1];
    float4 r1a = prelu4(a1a, ni, bb0, aa0), r1b = prelu4(a1b, ni, bb1, aa1);
    float4 r2a = prelu4(a2a, ni, bb0, aa0), r2b = prelu4(a2b, ni, bb1, aa1);
    r1a.x *= no; r1a.y *= no; r1a.z *= no; r1a.w *= no;
    r1b.x *= no; r1b.y *= no; r1b.z *= no; r1b.w *= no;
    r2a.x *= no; r2a.y *= no; r2a.z *= no; r2a.w *= no;
    r2b.x *= no; r2b.y *= no; r2b.z *= no; r2b.w *= no;
    h1[(size_t)d * 24 + tx * 2] = r1a;
    h1[(size_t)d * 24 + tx * 2 + 1] = r1b;
    h2[(size_t)d * 24 + tx * 2] = r2a;
    h2[(size_t)d * 24 + tx * 2 + 1] = r2b;
}

// ---------------- layer-2 dual-view SpMM over fp16 t table + fused final dot ----------------
__global__ __launch_bounds__(384) void spmm2_dual(
        const half8_t* __restrict__ th,
        const int* __restrict__ row_start, const int4* __restrict__ edge4,
        const int* __restrict__ order, const float* __restrict__ norm_in,
        const float* __restrict__ b2, const float* __restrict__ a2,
        const float* __restrict__ wsum, const float* __restrict__ bsum,
        float* __restrict__ outp, int N) {
    int g = blockIdx.x * 32 + threadIdx.y;
    int tx = threadIdx.x;
    int ty = threadIdx.y;
    bool valid = (g < N);
    int d = valid ? order[g] : 0;
    int beg = 0, end = 0;
    if (valid) { beg = row_start[d]; end = row_start[d + 1]; }
    const half8_t* t1 = th + tx;
    const half8_t* t2 = th + (size_t)N * 12 + tx;
    float4 a1a = {0,0,0,0}, a1b = {0,0,0,0}, a2a = {0,0,0,0}, a2b = {0,0,0,0};
    int j = beg;
    for (; j + 8 <= end; j += 8) {
        int s[8];
#pragma unroll
        for (int q = 0; q < 8; q++) s[q] = edge4[j + q].x;
        half8_t u[8], w[8];
#pragma unroll
        for (int q = 0; q < 8; q++) u[q] = t1[(size_t)s[q] * 12];
#pragma unroll
        for (int q = 0; q < 8; q++) w[q] = t2[(size_t)s[q] * 12];
#pragma unroll
        for (int q = 0; q < 8; q++) {
            fmah8(a1a, a1b, 1.f, u[q]);
            fmah8(a2a, a2b, 1.f, w[q]);
        }
    }
    for (; j < end; j++) {
        int s = edge4[j].x;
        fmah8(a1a, a1b, 1.f, t1[(size_t)s * 12]);
        fmah8(a2a, a2b, 1.f, t2[(size_t)s * 12]);
    }
    float ni = valid ? norm_in[d] : 0.f;
    float4 bb0 = ((const float4*)b2)[tx * 2], bb1 = ((const float4*)b2)[tx * 2 + 1];
    float4 aa0 = ((const float4*)a2)[tx * 2], aa1 = ((const float4*)a2)[tx * 2 + 1];
    float4 wv0 = ((const float4*)wsum)[tx * 2], wv1 = ((const float4*)wsum)[tx * 2 + 1];
    float4 r1a = prelu4(a1a, ni, bb0, aa0), r1b = prelu4(a1b, ni, bb1, aa1);
    float4 r2a = prelu4(a2a, ni, bb0, aa0), r2b = prelu4(a2b, ni, bb1, aa1);
    float p1 = r1a.x * wv0.x + r1a.y * wv0.y + r1a.z * wv0.z + r1a.w * wv0.w
             + r1b.x * wv1.x + r1b.y * wv1.y + r1b.z * wv1.z + r1b.w * wv1.w;
    float p2 = r2a.x * wv0.x + r2a.y * wv0.y + r2a.z * wv0.z + r2a.w * wv0.w
             + r2b.x * wv1.x + r2b.y * wv1.y + r2b.z * wv1.z + r2b.w * wv1.w;
    __shared__ float red1[32][12];
    __shared__ float red2[32][12];
    red1[ty][tx] = p1;
    red2[ty][tx] = p2;
    __syncthreads();
    if (tx == 0 && valid) {
        float s1 = 0.f, s2 = 0.f;
#pragma unroll
        for (int k = 0; k < 12; k++) { s1 += red1[ty][k]; s2 += red2[ty][k]; }
        outp[d] = s1 + bsum[0];
        outp[N + d] = s2 + bsum[0];
    }
}

extern "C" void kernel_launch(void* const* d_in, const int* in_sizes, int n_in,
                              void* d_out, int out_size, void* d_ws, size_t ws_size,
                              hipStream_t stream) {
    const float* x    = (const float*)d_in[0];
    const int*   src  = (const int*)d_in[1];
    const int*   dst  = (const int*)d_in[2];
    const int*   perm = (const int*)d_in[3];
    const float* W1   = (const float*)d_in[4];
    const float* b1   = (const float*)d_in[5];
    const float* a1   = (const float*)d_in[6];
    const float* W2   = (const float*)d_in[7];
    const float* b2   = (const float*)d_in[8];
    const float* a2   = (const float*)d_in[9];
    const float* Wm   = (const float*)d_in[10];
    const float* bm   = (const float*)d_in[11];
    float* out = (float*)d_out;

    int E = in_sizes[1];
    int N = in_sizes[3];
    int F = in_sizes[0] / N;               // 500
    int KP1 = ((F + GBK - 1) / GBK) * GBK; // 512

    size_t NP = ((size_t)N + 256) & ~(size_t)255;
    size_t EP = ((size_t)E + 255) & ~(size_t)255;
    int nb = (N + 255) / 256;
    size_t HB = ((size_t)256 * nb + 255) & ~(size_t)255;

    int* deg_out   = (int*)d_ws;          // NP
    int* deg_in    = deg_out + NP;        // NP
    int* pre       = deg_in + NP;         // NP
    int* row_start = pre + NP;            // NP
    int* cursor    = row_start + NP;      // NP
    int* order     = cursor + NP;         // NP
    int* bsums     = order + NP;          // 256
    int* hb        = bsums + 256;         // HB
    int* hpre      = hb + HB;             // HB
    int4* edge4    = (int4*)(hpre + HB);  // EP int4
    float* norm_out = (float*)(edge4 + EP);    // NP
    float* norm_in  = norm_out + NP;           // NP
    float* wsum     = norm_in + NP;            // 128
    float* bsum     = wsum + 128;              // 128
    unsigned short* w1th = (unsigned short*)(bsum + 128); // 96*KP1 pad 49664
    unsigned short* w1tl = w1th + 49664;
    unsigned short* w2th = w1tl + 49664;                  // 96*96 pad 9728
    unsigned short* w2tl = w2th + 9728;
    _Float16* yh = (_Float16*)(w2tl + 9728);      // N*96 fp16
    _Float16* th = yh + ((size_t)N * H96 + 256);  // 2N*96 fp16
    float* h1s = (float*)(th + (size_t)2 * N * H96 + 256);  // 2N*96 fp32

    hipMemsetAsync(deg_out, 0, 2 * NP * sizeof(int), stream);
    deg_kernel<<<(E + 255) / 256, 256, 0, stream>>>(src, dst, deg_out, deg_in, E);
    norm_kernel<<<(N + 255) / 256, 256, 0, stream>>>(deg_out, deg_in, norm_out, norm_in, N);

    scanA_kernel<<<nb, 256, 0, stream>>>(deg_in, pre, bsums, N);
    scanB_kernel<<<1, 256, 0, stream>>>(bsums, nb);
    rowfin_kernel<<<nb, 256, 0, stream>>>(pre, bsums, row_start, cursor, N, E);
    scatter_kernel<<<(E + 255) / 256, 256, 0, stream>>>(src, dst, perm, norm_out, cursor,
                                                        edge4, E);

    histblk_kernel<<<nb, 256, 0, stream>>>(deg_in, hb, N, nb);
    int n2 = 256 * nb;
    int nb2 = (n2 + 255) / 256;
    scanA_kernel<<<nb2, 256, 0, stream>>>(hb, hpre, bsums, n2);
    scanB_kernel<<<1, 256, 0, stream>>>(bsums, nb2);
    place2_kernel<<<nb, 256, 0, stream>>>(deg_in, hpre, bsums, order, N, nb);

    int wtot = 96 * KP1 + 96 * 96 + 96 + 1;
    weights_prep<<<(wtot + 255) / 256, 256, 0, stream>>>(W1, W2, Wm, bm, w1th, w1tl,
                                                         w2th, w2tl, wsum, bsum, F, KP1);

    // yh = fp16(x @ W1) via bf16x3 MFMA
    gemm_mfma<<<(N + GBM - 1) / GBM, 256, 0, stream>>>(x, w1th, w1tl, yh, N, F, KP1);

    int nsb = (N + 31) / 32;
    spmm1_dual<<<nsb, dim3(12, 32), 0, stream>>>(
        (const half8_t*)yh, row_start, edge4, order, norm_out, norm_in,
        b1, a1, (float4*)h1s, (float4*)(h1s + (size_t)N * H96), N);

    // th = fp16(h1s @ W2) via bf16x3 MFMA
    gemm_mfma<<<(2 * N + GBM - 1) / GBM, 256, 0, stream>>>(h1s, w2th, w2tl, th, 2 * N, H96, H96);

    spmm2_dual<<<nsb, dim3(12, 32), 0, stream>>>(
        (const half8_t*)th, row_start, edge4, order, norm_in, b2, a2,
        wsum, bsum, out, N);
}